// Round 7
// baseline (232.072 us; speedup 1.0000x reference)
//
#include <hip/hip_runtime.h>
#include <cstdint>
#include <cstddef>

typedef __attribute__((ext_vector_type(8))) short bf16x8;
typedef __attribute__((ext_vector_type(4))) float f32x4;

#define LOG2E 1.44269504f

__device__ __forceinline__ unsigned short f2bf(float x) {
  unsigned int u = __float_as_uint(x);
  u += 0x7FFFu + ((u >> 16) & 1u);   // RNE
  return (unsigned short)(u >> 16);
}
__device__ __forceinline__ unsigned short f2bf_trunc(float x) {
  return (unsigned short)(__float_as_uint(x) >> 16);
}

__device__ __forceinline__ void gload_lds16(const void* g, void* l) {
  __builtin_amdgcn_global_load_lds(
      (const __attribute__((address_space(1))) unsigned int*)g,
      (__attribute__((address_space(3))) unsigned int*)l, 16, 0, 0);
}

// ---------------- preprocessing: one merged dispatch ----------------

__global__ void preproc(const float* __restrict__ x_q, const float* __restrict__ x_kv,
                        const float* __restrict__ Wq, const float* __restrict__ Wm,
                        const float* __restrict__ Wg,
                        const float* __restrict__ amp, const float* __restrict__ off,
                        const float* __restrict__ sharp,
                        ushort4* __restrict__ bXq, ushort4* __restrict__ bXkv,
                        unsigned short* __restrict__ dWq, unsigned short* __restrict__ dWm,
                        unsigned short* __restrict__ dWg, float* __restrict__ tab) {
  __shared__ float tile[32][33];
  const int blk = blockIdx.x;
  if (blk < 8192) {
    int i = blk * 256 + threadIdx.x;
    float4 v;
    ushort4* d;
    if (i < (1 << 20)) { v = ((const float4*)x_q)[i]; d = bXq + i; }
    else { int j = i - (1 << 20); v = ((const float4*)x_kv)[j]; d = bXkv + j; }
    ushort4 o;
    o.x = f2bf(v.x); o.y = f2bf(v.y); o.z = f2bf(v.z); o.w = f2bf(v.w);
    *d = o;
  } else if (blk < 14336) {
    int idx = blk - 8192;
    int z = idx >> 11, rem = idx & 2047;
    int bx = rem & 63, by = rem >> 6;
    const float* src = z == 0 ? Wq : (z == 1 ? Wm : Wg);
    unsigned short* dst = z == 0 ? dWq : (z == 1 ? dWm : dWg);
    int N = z == 0 ? 1024 : 2048;
    int nb = bx * 32, kb = by * 32;
    if (nb >= N) return;
    int tx = threadIdx.x & 31, ty = threadIdx.x >> 5;
#pragma unroll
    for (int r = ty; r < 32; r += 8)
      tile[r][tx] = src[(size_t)(kb + r) * N + nb + tx];
    __syncthreads();
#pragma unroll
    for (int r = ty; r < 32; r += 8)
      dst[(size_t)(nb + r) * 1024 + kb + tx] = f2bf(tile[tx][r]);
  } else {
    int h = blk - 14336;
    for (int idx = threadIdx.x; idx < 2047; idx += 256) {
      float d = (float)(idx - 1023);
      float acc = 0.f;
#pragma unroll
      for (int k = 0; k < 21; ++k) {
        float dd = d - off[h * 21 + k];
        acc += amp[h * 21 + k] * __expf(-fabsf(sharp[h * 21 + k]) * dd * dd);
      }
      tab[h * 2047 + idx] = acc * LOG2E;
    }
  }
}

// ---------------- fused QKV GEMM: 2 waves x (64x128) wave-tiles ----------------
// 128 threads, block tile 128x128, grid (24,32)=768 = 3 blocks/CU exactly.
// 12 ds_read_b128 : 32 MFMA per wave-iter (42.7 FLOP/LDS-byte).

__global__ __launch_bounds__(128, 2)
void qkv_gemm(const unsigned short* __restrict__ Xq,
              const unsigned short* __restrict__ Xkv,
              const unsigned short* __restrict__ WqT,
              const unsigned short* __restrict__ WmT,
              unsigned short* __restrict__ qbuf,
              unsigned short* __restrict__ kbuf,
              unsigned short* __restrict__ vtbuf) {
  __shared__ unsigned short sA[2][128 * 32];
  __shared__ unsigned short sB[2][128 * 32];
  const int bx = blockIdx.x;
  const bool isQ = bx < 8;
  const int ntile = (isQ ? bx : bx - 8) << 7;
  const unsigned short* A = isQ ? Xq : Xkv;
  const unsigned short* B = (isQ ? WqT : WmT) + (size_t)ntile * 1024;
  const int t = threadIdx.x, lane = t & 63, w = t >> 6;
  const int mtile = blockIdx.y << 7;
  const int c = lane & 15, g = lane >> 4;
  // staging: wave w stages rows [w*64, w*64+64): 4 issues x (16 rows x 4 chunks)
  const int rr = lane >> 2, cc = (lane & 3) << 3;
  const unsigned short* aBase = A + (size_t)(mtile + w * 64 + rr) * 1024 + cc;
  const unsigned short* bBase = B + (size_t)(w * 64 + rr) * 1024 + cc;
  const int lo = (w * 64 + rr) * 32 + cc;   // + j*512 per issue

#pragma unroll
  for (int j = 0; j < 4; ++j) {
    gload_lds16(aBase + (size_t)j * 16 * 1024, &sA[0][lo + j * 512]);
    gload_lds16(bBase + (size_t)j * 16 * 1024, &sB[0][lo + j * 512]);
  }
  __syncthreads();

  f32x4 acc[4][8] = {};
  for (int kt = 0; kt < 32; ++kt) {
    const int cur = kt & 1;
    if (kt + 1 < 32) {
      const int ko = (kt + 1) * 32;
#pragma unroll
      for (int j = 0; j < 4; ++j) {
        gload_lds16(aBase + (size_t)j * 16 * 1024 + ko, &sA[1 - cur][lo + j * 512]);
        gload_lds16(bBase + (size_t)j * 16 * 1024 + ko, &sB[1 - cur][lo + j * 512]);
      }
    }
    bf16x8 af[4], bfr[8];
#pragma unroll
    for (int i = 0; i < 4; ++i)
      af[i] = *(const bf16x8*)&sA[cur][(w * 64 + i * 16 + c) * 32 + g * 8];
#pragma unroll
    for (int j = 0; j < 8; ++j)
      bfr[j] = *(const bf16x8*)&sB[cur][(j * 16 + c) * 32 + g * 8];
#pragma unroll
    for (int i = 0; i < 4; ++i)
#pragma unroll
      for (int j = 0; j < 8; ++j)
        acc[i][j] = __builtin_amdgcn_mfma_f32_16x16x32_bf16(af[i], bfr[j], acc[i][j], 0, 0, 0);
    __syncthreads();
  }

  const int row0 = mtile + w * 64 + (g << 2);
  if (isQ) {
#pragma unroll
    for (int i = 0; i < 4; ++i)
#pragma unroll
      for (int j = 0; j < 8; ++j) {
        int r = row0 + i * 16, cl = ntile + j * 16 + c;
#pragma unroll
        for (int ri = 0; ri < 4; ++ri)
          qbuf[(size_t)(r + ri) * 1024 + cl] = f2bf(acc[i][j][ri] * (0.125f * LOG2E));
      }
  } else {
#pragma unroll
    for (int i = 0; i < 4; ++i)
#pragma unroll
      for (int j = 0; j < 8; ++j) {
        int r = row0 + i * 16, cl = ntile + j * 16 + c;
        if (cl < 1024) {
#pragma unroll
          for (int ri = 0; ri < 4; ++ri)
            kbuf[(size_t)(r + ri) * 1024 + cl] = f2bf(acc[i][j][ri]);
        } else {
          int d = cl - 1024;
          int hh = d >> 6, dh = d & 63;
          int bb = r >> 10, ll = r & 1023;
          ushort4 pk;
          pk.x = f2bf(acc[i][j][0]);
          pk.y = f2bf(acc[i][j][1]);
          pk.z = f2bf(acc[i][j][2]);
          pk.w = f2bf(acc[i][j][3]);
          *(ushort4*)&vtbuf[((size_t)((bb * 16 + hh) * 64 + dh) << 10) + ll] = pk;
        }
      }
  }
}

// ---------------- flash attention v6 (unchanged from R6) ----------------

__global__ __launch_bounds__(512)
void attn_kernel(const unsigned short* __restrict__ qbuf,
                 const unsigned short* __restrict__ kbuf,
                 const unsigned short* __restrict__ vtbuf,
                 const float* __restrict__ biasTab,
                 unsigned short* __restrict__ attnb) {
  const int h = blockIdx.x & 15, b = blockIdx.x >> 4, qt = blockIdx.y;
  __shared__ unsigned short sK[2][64 * 64];
  __shared__ unsigned short sV[3][64 * 64];
  __shared__ unsigned short sP[2][128 * 64];
  __shared__ float sLsum[2][128];
  const int t = threadIdx.x, lane = t & 63, w = t >> 6;
  const int c = lane & 15, g = lane >> 4;
  const int rg = w >> 1, cg = w & 1;

  const int r = t >> 3, ch = (t & 7) ^ (r & 7);

  const unsigned short* qsrc = qbuf + (size_t)(b * 1024 + qt * 128) * 1024 + h * 64;
  const unsigned short* ksrc = kbuf + (size_t)(b * 1024) * 1024 + h * 64;
  const unsigned short* vsrc = vtbuf + (size_t)((b * 16 + h) * 64) * 1024;

  unsigned short* sQ = &sP[0][0];
  gload_lds16(qsrc + (size_t)r * 1024 + ch * 8, &sQ[t * 8]);
  gload_lds16(qsrc + (size_t)(r + 64) * 1024 + ch * 8, &sQ[4096 + t * 8]);
  gload_lds16(ksrc + (size_t)r * 1024 + ch * 8, &sK[0][t * 8]);
  gload_lds16(vsrc + (size_t)r * 1024 + ch * 8, &sV[0][t * 8]);
  __syncthreads();

  bf16x8 aq[2][2];
#pragma unroll
  for (int rf = 0; rf < 2; ++rf) {
    int row = rg * 32 + rf * 16 + c;
#pragma unroll
    for (int ks = 0; ks < 2; ++ks)
      aq[rf][ks] = *(const bf16x8*)&sQ[row * 64 + (((ks * 4 + g) ^ (row & 7)) * 8)];
  }
  __syncthreads();

  f32x4 o[2][2] = {};
  float lsum[2][4] = {};
  const float* bb = biasTab + h * 2047 + 1023 + cg * 32 + c - qt * 128 - rg * 32 - g * 4;

  int vcur = 0, vnx = 1;
  for (int kv = 0; kv < 16; ++kv) {
    const int cur = kv & 1;

    const float* bk = bb + kv * 64;
    f32x4 s[2][2];
#pragma unroll
    for (int rf = 0; rf < 2; ++rf)
#pragma unroll
      for (int nf = 0; nf < 2; ++nf)
#pragma unroll
        for (int ri = 0; ri < 4; ++ri)
          s[rf][nf][ri] = bk[(nf - rf) * 16 - ri];

    if (kv + 1 < 16) {
      gload_lds16(ksrc + (size_t)((kv + 1) * 64 + r) * 1024 + ch * 8, &sK[1 - cur][t * 8]);
      gload_lds16(vsrc + (size_t)r * 1024 + (kv + 1) * 64 + ch * 8, &sV[vnx][t * 8]);
    }

#pragma unroll
    for (int nf = 0; nf < 2; ++nf) {
      int krow = cg * 32 + nf * 16 + c;
      bf16x8 k0 = *(const bf16x8*)&sK[cur][krow * 64 + (((g) ^ (krow & 7)) * 8)];
      bf16x8 k1 = *(const bf16x8*)&sK[cur][krow * 64 + (((4 + g) ^ (krow & 7)) * 8)];
#pragma unroll
      for (int rf = 0; rf < 2; ++rf) {
        s[rf][nf] = __builtin_amdgcn_mfma_f32_16x16x32_bf16(aq[rf][0], k0, s[rf][nf], 0, 0, 0);
        s[rf][nf] = __builtin_amdgcn_mfma_f32_16x16x32_bf16(aq[rf][1], k1, s[rf][nf], 0, 0, 0);
      }
    }

#pragma unroll
    for (int rf = 0; rf < 2; ++rf)
#pragma unroll
      for (int nf = 0; nf < 2; ++nf)
#pragma unroll
        for (int ri = 0; ri < 4; ++ri) {
          float e = exp2f(s[rf][nf][ri]);
          lsum[rf][ri] += e;
          int prow = rg * 32 + rf * 16 + g * 4 + ri;
          int chunk = cg * 4 + nf * 2 + (c >> 3);
          sP[cur][prow * 64 + ((chunk ^ (prow & 7)) * 8) + (c & 7)] = f2bf_trunc(e);
        }
    __syncthreads();

    bf16x8 ap[2][2];
#pragma unroll
    for (int rf = 0; rf < 2; ++rf) {
      int row = rg * 32 + rf * 16 + c;
#pragma unroll
      for (int ks = 0; ks < 2; ++ks)
        ap[rf][ks] = *(const bf16x8*)&sP[cur][row * 64 + (((ks * 4 + g) ^ (row & 7)) * 8)];
    }
#pragma unroll
    for (int df = 0; df < 2; ++df) {
      int vrow = cg * 32 + df * 16 + c;
      bf16x8 v0 = *(const bf16x8*)&sV[vcur][vrow * 64 + (((g) ^ (vrow & 7)) * 8)];
      bf16x8 v1 = *(const bf16x8*)&sV[vcur][vrow * 64 + (((4 + g) ^ (vrow & 7)) * 8)];
#pragma unroll
      for (int rf = 0; rf < 2; ++rf) {
        o[rf][df] = __builtin_amdgcn_mfma_f32_16x16x32_bf16(ap[rf][0], v0, o[rf][df], 0, 0, 0);
        o[rf][df] = __builtin_amdgcn_mfma_f32_16x16x32_bf16(ap[rf][1], v1, o[rf][df], 0, 0, 0);
      }
    }
    vcur = vnx;
    vnx = (vnx == 2) ? 0 : vnx + 1;
  }

#pragma unroll
  for (int off = 1; off < 16; off <<= 1)
#pragma unroll
    for (int rf = 0; rf < 2; ++rf)
#pragma unroll
      for (int ri = 0; ri < 4; ++ri)
        lsum[rf][ri] += __shfl_xor(lsum[rf][ri], off, 64);
  if (c == 0) {
#pragma unroll
    for (int rf = 0; rf < 2; ++rf)
#pragma unroll
      for (int ri = 0; ri < 4; ++ri)
        sLsum[cg][rg * 32 + rf * 16 + g * 4 + ri] = lsum[rf][ri];
  }
  __syncthreads();

  unsigned short* obase = attnb +
      (size_t)(b * 1024 + qt * 128 + rg * 32 + g * 4) * 1024 + h * 64 + cg * 32 + c;
#pragma unroll
  for (int rf = 0; rf < 2; ++rf)
#pragma unroll
    for (int ri = 0; ri < 4; ++ri) {
      int row = rg * 32 + rf * 16 + g * 4 + ri;
      float rinv = 1.0f / (sLsum[0][row] + sLsum[1][row]);
#pragma unroll
      for (int df = 0; df < 2; ++df)
        obase[(size_t)(rf * 16 + ri) * 1024 + df * 16] = f2bf(o[rf][df][ri] * rinv);
    }
}

// ---------------- output GEMM: 2 waves x (64x128), a/b interleaved, fused sigmoid ----------------
// sB rows p: q=p>>5 -> q even: a-cols nb*64+(q>>1)*32+(p&31); q odd: b-cols (+1024).
// B-frags j: {0,1,4,5}=a, {2,3,6,7}=paired b. grid (16,32)=512 = 2 blocks/CU.

__global__ __launch_bounds__(128, 2)
void out_gemm(const unsigned short* __restrict__ A,
              const unsigned short* __restrict__ WgT,
              const float* __restrict__ bg,
              float* __restrict__ out) {
  __shared__ unsigned short sA[2][128 * 32];
  __shared__ unsigned short sB[2][128 * 32];
  const int nb = blockIdx.x;
  const int mtile = blockIdx.y << 7;
  const int t = threadIdx.x, lane = t & 63, w = t >> 6;
  const int c = lane & 15, g = lane >> 4;
  const int rr = lane >> 2, cc = (lane & 3) << 3;
  const unsigned short* aBase = A + (size_t)(mtile + w * 64 + rr) * 1024 + cc;
  // per-issue B base rows (j=0..3 for this wave): p = w*64 + j*16
  const unsigned short* bBase[4];
#pragma unroll
  for (int j = 0; j < 4; ++j) {
    int p = w * 64 + j * 16;
    int q = p >> 5;
    int grow = ((q & 1) ? 1024 : 0) + nb * 64 + (q >> 1) * 32 + (p & 31) + rr;
    bBase[j] = WgT + (size_t)grow * 1024 + cc;
  }
  const int lo = (w * 64 + rr) * 32 + cc;

#pragma unroll
  for (int j = 0; j < 4; ++j) {
    gload_lds16(aBase + (size_t)j * 16 * 1024, &sA[0][lo + j * 512]);
    gload_lds16(bBase[j], &sB[0][lo + j * 512]);
  }
  __syncthreads();

  f32x4 acc[4][8] = {};
  for (int kt = 0; kt < 32; ++kt) {
    const int cur = kt & 1;
    if (kt + 1 < 32) {
      const int ko = (kt + 1) * 32;
#pragma unroll
      for (int j = 0; j < 4; ++j) {
        gload_lds16(aBase + (size_t)j * 16 * 1024 + ko, &sA[1 - cur][lo + j * 512]);
        gload_lds16(bBase[j] + ko, &sB[1 - cur][lo + j * 512]);
      }
    }
    bf16x8 af[4], bfr[8];
#pragma unroll
    for (int i = 0; i < 4; ++i)
      af[i] = *(const bf16x8*)&sA[cur][(w * 64 + i * 16 + c) * 32 + g * 8];
#pragma unroll
    for (int j = 0; j < 8; ++j)
      bfr[j] = *(const bf16x8*)&sB[cur][(j * 16 + c) * 32 + g * 8];
#pragma unroll
    for (int i = 0; i < 4; ++i)
#pragma unroll
      for (int j = 0; j < 8; ++j)
        acc[i][j] = __builtin_amdgcn_mfma_f32_16x16x32_bf16(af[i], bfr[j], acc[i][j], 0, 0, 0);
    __syncthreads();
  }

  const int row0 = mtile + w * 64 + (g << 2);
#pragma unroll
  for (int i = 0; i < 4; ++i) {
#pragma unroll
    for (int jj = 0; jj < 4; ++jj) {
      int ja = (jj & 1) + (jj >> 1) * 4;        // 0,1,4,5
      int col = nb * 64 + (jj >> 1) * 32 + (jj & 1) * 16 + c;
      float ba = bg[col];
      float bbv = bg[1024 + col];
#pragma unroll
      for (int ri = 0; ri < 4; ++ri) {
        float av = acc[i][ja][ri] + ba;
        float bv = acc[i][ja + 2][ri] + bbv;
        out[(size_t)(row0 + i * 16 + ri) * 1024 + col] = av / (1.f + exp2f(-LOG2E * bv));
      }
    }
  }
}

// ---------------- launch ----------------

extern "C" void kernel_launch(void* const* d_in, const int* in_sizes, int n_in,
                              void* d_out, int out_size, void* d_ws, size_t ws_size,
                              hipStream_t stream) {
  const float* x_q   = (const float*)d_in[0];
  const float* x_kv  = (const float*)d_in[1];
  const float* Wq    = (const float*)d_in[2];
  const float* Wm    = (const float*)d_in[3];
  const float* Wg    = (const float*)d_in[4];
  const float* bg    = (const float*)d_in[5];
  const float* amp   = (const float*)d_in[6];
  const float* off   = (const float*)d_in[7];
  const float* sharp = (const float*)d_in[8];
  float* out = (float*)d_out;

  char* ws = (char*)d_ws;
  size_t o = 0;
  auto alloc = [&](size_t bytes) {
    char* p = ws + o;
    o += (bytes + 255) & ~(size_t)255;
    return p;
  };
  unsigned short* bXq   = (unsigned short*)alloc(4096ull * 1024 * 2);
  unsigned short* bXkv  = (unsigned short*)alloc(4096ull * 1024 * 2);
  unsigned short* bWqT  = (unsigned short*)alloc(1024ull * 1024 * 2);
  unsigned short* bWmT  = (unsigned short*)alloc(2048ull * 1024 * 2);
  unsigned short* bWgT  = (unsigned short*)alloc(2048ull * 1024 * 2);
  float*          biasT = (float*)alloc(16ull * 2047 * 4);
  unsigned short* qbuf  = (unsigned short*)alloc(4096ull * 1024 * 2);
  unsigned short* kbuf  = (unsigned short*)alloc(4096ull * 1024 * 2);
  unsigned short* vtbuf = (unsigned short*)alloc(4096ull * 1024 * 2);
  unsigned short* attnb = (unsigned short*)alloc(4096ull * 1024 * 2);
  if (ws_size < o) return;

  preproc<<<14352, 256, 0, stream>>>(x_q, x_kv, Wq, Wm, Wg, amp, off, sharp,
                                     (ushort4*)bXq, (ushort4*)bXkv,
                                     bWqT, bWmT, bWgT, biasT);
  qkv_gemm<<<dim3(24, 32), 128, 0, stream>>>(bXq, bXkv, bWqT, bWmT, qbuf, kbuf, vtbuf);
  attn_kernel<<<dim3(64, 8), 512, 0, stream>>>(qbuf, kbuf, vtbuf, biasT, attnb);
  out_gemm<<<dim3(16, 32), 128, 0, stream>>>(attnb, bWgT, bg, out);
}

// Round 8
// 216.497 us; speedup vs baseline: 1.0719x; 1.0719x over previous
//
#include <hip/hip_runtime.h>
#include <cstdint>
#include <cstddef>

typedef __attribute__((ext_vector_type(8))) short bf16x8;
typedef __attribute__((ext_vector_type(4))) float f32x4;

#define LOG2E 1.44269504f

__device__ __forceinline__ unsigned short f2bf(float x) {
  unsigned int u = __float_as_uint(x);
  u += 0x7FFFu + ((u >> 16) & 1u);   // RNE
  return (unsigned short)(u >> 16);
}
__device__ __forceinline__ unsigned short f2bf_trunc(float x) {
  return (unsigned short)(__float_as_uint(x) >> 16);
}

__device__ __forceinline__ void gload_lds16(const void* g, void* l) {
  __builtin_amdgcn_global_load_lds(
      (const __attribute__((address_space(1))) unsigned int*)g,
      (__attribute__((address_space(3))) unsigned int*)l, 16, 0, 0);
}

// ---------------- preprocessing: one merged dispatch ----------------

__global__ void preproc(const float* __restrict__ x_q, const float* __restrict__ x_kv,
                        const float* __restrict__ Wq, const float* __restrict__ Wm,
                        const float* __restrict__ Wg,
                        const float* __restrict__ amp, const float* __restrict__ off,
                        const float* __restrict__ sharp,
                        ushort4* __restrict__ bXq, ushort4* __restrict__ bXkv,
                        unsigned short* __restrict__ dWq, unsigned short* __restrict__ dWm,
                        unsigned short* __restrict__ dWg, float* __restrict__ tab) {
  __shared__ float tile[32][33];
  const int blk = blockIdx.x;
  if (blk < 8192) {
    int i = blk * 256 + threadIdx.x;
    float4 v;
    ushort4* d;
    if (i < (1 << 20)) { v = ((const float4*)x_q)[i]; d = bXq + i; }
    else { int j = i - (1 << 20); v = ((const float4*)x_kv)[j]; d = bXkv + j; }
    ushort4 o;
    o.x = f2bf(v.x); o.y = f2bf(v.y); o.z = f2bf(v.z); o.w = f2bf(v.w);
    *d = o;
  } else if (blk < 14336) {
    int idx = blk - 8192;
    int z = idx >> 11, rem = idx & 2047;
    int bx = rem & 63, by = rem >> 6;
    const float* src = z == 0 ? Wq : (z == 1 ? Wm : Wg);
    unsigned short* dst = z == 0 ? dWq : (z == 1 ? dWm : dWg);
    int N = z == 0 ? 1024 : 2048;
    int nb = bx * 32, kb = by * 32;
    if (nb >= N) return;
    int tx = threadIdx.x & 31, ty = threadIdx.x >> 5;
#pragma unroll
    for (int r = ty; r < 32; r += 8)
      tile[r][tx] = src[(size_t)(kb + r) * N + nb + tx];
    __syncthreads();
#pragma unroll
    for (int r = ty; r < 32; r += 8)
      dst[(size_t)(nb + r) * 1024 + kb + tx] = f2bf(tile[tx][r]);
  } else {
    int h = blk - 14336;
    for (int idx = threadIdx.x; idx < 2047; idx += 256) {
      float d = (float)(idx - 1023);
      float acc = 0.f;
#pragma unroll
      for (int k = 0; k < 21; ++k) {
        float dd = d - off[h * 21 + k];
        acc += amp[h * 21 + k] * __expf(-fabsf(sharp[h * 21 + k]) * dd * dd);
      }
      tab[h * 2047 + idx] = acc * LOG2E;
    }
  }
}

// ---------------- fused QKV GEMM (R4 body, XCD A-locality grid) ----------------
// grid (32, 24): x = M-tile -> XCD = mtile%8 (A stays L2-resident per XCD),
// y = combined N-tile (y<8: Q, y>=8: K/V).

__global__ __launch_bounds__(256)
void qkv_gemm(const unsigned short* __restrict__ Xq,
              const unsigned short* __restrict__ Xkv,
              const unsigned short* __restrict__ WqT,
              const unsigned short* __restrict__ WmT,
              unsigned short* __restrict__ qbuf,
              unsigned short* __restrict__ kbuf,
              unsigned short* __restrict__ vtbuf) {
  __shared__ unsigned short sA[2][128 * 32];
  __shared__ unsigned short sB[2][128 * 32];
  const int bx = blockIdx.y;
  const bool isQ = bx < 8;
  const int ntile = (isQ ? bx : bx - 8) << 7;
  const unsigned short* A = isQ ? Xq : Xkv;
  const unsigned short* B = (isQ ? WqT : WmT) + (size_t)ntile * 1024;
  const int t = threadIdx.x, lane = t & 63, w = t >> 6;
  const int wm = (w >> 1) << 6, wn = (w & 1) << 6;
  const int mtile = blockIdx.x << 7;
  const int c = lane & 15, g = lane >> 4;
  const int srow = t >> 2, scol = (t & 3) << 3;
  const unsigned short* aP = A + (size_t)(mtile + srow) * 1024 + scol;
  const unsigned short* bP = B + (size_t)srow * 1024 + scol;
  const int lo = srow * 32 + scol;

  gload_lds16(aP, &sA[0][lo]);
  gload_lds16(aP + 64 * 1024, &sA[0][lo + 64 * 32]);
  gload_lds16(bP, &sB[0][lo]);
  gload_lds16(bP + 64 * 1024, &sB[0][lo + 64 * 32]);
  __syncthreads();

  f32x4 acc[4][4] = {};
  for (int kt = 0; kt < 32; ++kt) {
    const int cur = kt & 1;
    if (kt + 1 < 32) {
      const int ko = (kt + 1) * 32;
      gload_lds16(aP + ko, &sA[1 - cur][lo]);
      gload_lds16(aP + 64 * 1024 + ko, &sA[1 - cur][lo + 64 * 32]);
      gload_lds16(bP + ko, &sB[1 - cur][lo]);
      gload_lds16(bP + 64 * 1024 + ko, &sB[1 - cur][lo + 64 * 32]);
    }
    bf16x8 af[4], bfr[4];
#pragma unroll
    for (int i = 0; i < 4; ++i) {
      af[i]  = *(const bf16x8*)&sA[cur][(wm + i * 16 + c) * 32 + g * 8];
      bfr[i] = *(const bf16x8*)&sB[cur][(wn + i * 16 + c) * 32 + g * 8];
    }
#pragma unroll
    for (int i = 0; i < 4; ++i)
#pragma unroll
      for (int j = 0; j < 4; ++j)
        acc[i][j] = __builtin_amdgcn_mfma_f32_16x16x32_bf16(af[i], bfr[j], acc[i][j], 0, 0, 0);
    __syncthreads();
  }

  const int row0 = mtile + wm + (g << 2);
  const int col0 = ntile + wn + c;
  if (isQ) {
#pragma unroll
    for (int i = 0; i < 4; ++i)
#pragma unroll
      for (int j = 0; j < 4; ++j) {
        int r = row0 + i * 16, cl = col0 + j * 16;
#pragma unroll
        for (int ri = 0; ri < 4; ++ri)
          qbuf[(size_t)(r + ri) * 1024 + cl] = f2bf(acc[i][j][ri] * (0.125f * LOG2E));
      }
  } else {
#pragma unroll
    for (int i = 0; i < 4; ++i)
#pragma unroll
      for (int j = 0; j < 4; ++j) {
        int r = row0 + i * 16, cl = col0 + j * 16;
        if (cl < 1024) {
#pragma unroll
          for (int ri = 0; ri < 4; ++ri)
            kbuf[(size_t)(r + ri) * 1024 + cl] = f2bf(acc[i][j][ri]);
        } else {
          int d = cl - 1024;
          int hh = d >> 6, dh = d & 63;
          int bb = r >> 10, ll = r & 1023;
          ushort4 pk;
          pk.x = f2bf(acc[i][j][0]);
          pk.y = f2bf(acc[i][j][1]);
          pk.z = f2bf(acc[i][j][2]);
          pk.w = f2bf(acc[i][j][3]);
          *(ushort4*)&vtbuf[((size_t)((bb * 16 + hh) * 64 + dh) << 10) + ll] = pk;
        }
      }
  }
}

// ---------------- flash attention v6 (R6, unchanged) ----------------

__global__ __launch_bounds__(512)
void attn_kernel(const unsigned short* __restrict__ qbuf,
                 const unsigned short* __restrict__ kbuf,
                 const unsigned short* __restrict__ vtbuf,
                 const float* __restrict__ biasTab,
                 unsigned short* __restrict__ attnb) {
  const int h = blockIdx.x & 15, b = blockIdx.x >> 4, qt = blockIdx.y;
  __shared__ unsigned short sK[2][64 * 64];
  __shared__ unsigned short sV[3][64 * 64];
  __shared__ unsigned short sP[2][128 * 64];
  __shared__ float sLsum[2][128];
  const int t = threadIdx.x, lane = t & 63, w = t >> 6;
  const int c = lane & 15, g = lane >> 4;
  const int rg = w >> 1, cg = w & 1;

  const int r = t >> 3, ch = (t & 7) ^ (r & 7);

  const unsigned short* qsrc = qbuf + (size_t)(b * 1024 + qt * 128) * 1024 + h * 64;
  const unsigned short* ksrc = kbuf + (size_t)(b * 1024) * 1024 + h * 64;
  const unsigned short* vsrc = vtbuf + (size_t)((b * 16 + h) * 64) * 1024;

  unsigned short* sQ = &sP[0][0];
  gload_lds16(qsrc + (size_t)r * 1024 + ch * 8, &sQ[t * 8]);
  gload_lds16(qsrc + (size_t)(r + 64) * 1024 + ch * 8, &sQ[4096 + t * 8]);
  gload_lds16(ksrc + (size_t)r * 1024 + ch * 8, &sK[0][t * 8]);
  gload_lds16(vsrc + (size_t)r * 1024 + ch * 8, &sV[0][t * 8]);
  __syncthreads();

  bf16x8 aq[2][2];
#pragma unroll
  for (int rf = 0; rf < 2; ++rf) {
    int row = rg * 32 + rf * 16 + c;
#pragma unroll
    for (int ks = 0; ks < 2; ++ks)
      aq[rf][ks] = *(const bf16x8*)&sQ[row * 64 + (((ks * 4 + g) ^ (row & 7)) * 8)];
  }
  __syncthreads();

  f32x4 o[2][2] = {};
  float lsum[2][4] = {};
  const float* bb = biasTab + h * 2047 + 1023 + cg * 32 + c - qt * 128 - rg * 32 - g * 4;

  int vcur = 0, vnx = 1;
  for (int kv = 0; kv < 16; ++kv) {
    const int cur = kv & 1;

    const float* bk = bb + kv * 64;
    f32x4 s[2][2];
#pragma unroll
    for (int rf = 0; rf < 2; ++rf)
#pragma unroll
      for (int nf = 0; nf < 2; ++nf)
#pragma unroll
        for (int ri = 0; ri < 4; ++ri)
          s[rf][nf][ri] = bk[(nf - rf) * 16 - ri];

    if (kv + 1 < 16) {
      gload_lds16(ksrc + (size_t)((kv + 1) * 64 + r) * 1024 + ch * 8, &sK[1 - cur][t * 8]);
      gload_lds16(vsrc + (size_t)r * 1024 + (kv + 1) * 64 + ch * 8, &sV[vnx][t * 8]);
    }

#pragma unroll
    for (int nf = 0; nf < 2; ++nf) {
      int krow = cg * 32 + nf * 16 + c;
      bf16x8 k0 = *(const bf16x8*)&sK[cur][krow * 64 + (((g) ^ (krow & 7)) * 8)];
      bf16x8 k1 = *(const bf16x8*)&sK[cur][krow * 64 + (((4 + g) ^ (krow & 7)) * 8)];
#pragma unroll
      for (int rf = 0; rf < 2; ++rf) {
        s[rf][nf] = __builtin_amdgcn_mfma_f32_16x16x32_bf16(aq[rf][0], k0, s[rf][nf], 0, 0, 0);
        s[rf][nf] = __builtin_amdgcn_mfma_f32_16x16x32_bf16(aq[rf][1], k1, s[rf][nf], 0, 0, 0);
      }
    }

#pragma unroll
    for (int rf = 0; rf < 2; ++rf)
#pragma unroll
      for (int nf = 0; nf < 2; ++nf)
#pragma unroll
        for (int ri = 0; ri < 4; ++ri) {
          float e = exp2f(s[rf][nf][ri]);
          lsum[rf][ri] += e;
          int prow = rg * 32 + rf * 16 + g * 4 + ri;
          int chunk = cg * 4 + nf * 2 + (c >> 3);
          sP[cur][prow * 64 + ((chunk ^ (prow & 7)) * 8) + (c & 7)] = f2bf_trunc(e);
        }
    __syncthreads();

    bf16x8 ap[2][2];
#pragma unroll
    for (int rf = 0; rf < 2; ++rf) {
      int row = rg * 32 + rf * 16 + c;
#pragma unroll
      for (int ks = 0; ks < 2; ++ks)
        ap[rf][ks] = *(const bf16x8*)&sP[cur][row * 64 + (((ks * 4 + g) ^ (row & 7)) * 8)];
    }
#pragma unroll
    for (int df = 0; df < 2; ++df) {
      int vrow = cg * 32 + df * 16 + c;
      bf16x8 v0 = *(const bf16x8*)&sV[vcur][vrow * 64 + (((g) ^ (vrow & 7)) * 8)];
      bf16x8 v1 = *(const bf16x8*)&sV[vcur][vrow * 64 + (((4 + g) ^ (vrow & 7)) * 8)];
#pragma unroll
      for (int rf = 0; rf < 2; ++rf) {
        o[rf][df] = __builtin_amdgcn_mfma_f32_16x16x32_bf16(ap[rf][0], v0, o[rf][df], 0, 0, 0);
        o[rf][df] = __builtin_amdgcn_mfma_f32_16x16x32_bf16(ap[rf][1], v1, o[rf][df], 0, 0, 0);
      }
    }
    vcur = vnx;
    vnx = (vnx == 2) ? 0 : vnx + 1;
  }

#pragma unroll
  for (int off = 1; off < 16; off <<= 1)
#pragma unroll
    for (int rf = 0; rf < 2; ++rf)
#pragma unroll
      for (int ri = 0; ri < 4; ++ri)
        lsum[rf][ri] += __shfl_xor(lsum[rf][ri], off, 64);
  if (c == 0) {
#pragma unroll
    for (int rf = 0; rf < 2; ++rf)
#pragma unroll
      for (int ri = 0; ri < 4; ++ri)
        sLsum[cg][rg * 32 + rf * 16 + g * 4 + ri] = lsum[rf][ri];
  }
  __syncthreads();

  unsigned short* obase = attnb +
      (size_t)(b * 1024 + qt * 128 + rg * 32 + g * 4) * 1024 + h * 64 + cg * 32 + c;
#pragma unroll
  for (int rf = 0; rf < 2; ++rf)
#pragma unroll
    for (int ri = 0; ri < 4; ++ri) {
      int row = rg * 32 + rf * 16 + g * 4 + ri;
      float rinv = 1.0f / (sLsum[0][row] + sLsum[1][row]);
#pragma unroll
      for (int df = 0; df < 2; ++df)
        obase[(size_t)(rf * 16 + ri) * 1024 + df * 16] = f2bf(o[rf][df][ri] * rinv);
    }
}

// ---------------- output GEMM (R4 body, XCD A-locality grid) ----------------
// grid (32, 16): x = M-tile -> XCD = mtile%8, y = N-pair tile.
// sB rows 0..63 = Wg cols nb*64.. (a), 64..127 = +1024 (b).

__global__ __launch_bounds__(256)
void out_gemm(const unsigned short* __restrict__ A,
              const unsigned short* __restrict__ WgT,
              const float* __restrict__ bg,
              float* __restrict__ out) {
  __shared__ unsigned short sA[2][128 * 32];
  __shared__ unsigned short sB[2][128 * 32];
  const int nb = blockIdx.y;
  const int mtile = blockIdx.x << 7;
  const int t = threadIdx.x, lane = t & 63, w = t >> 6;
  const int c = lane & 15, g = lane >> 4;
  const int srow = t >> 2, scol = (t & 3) << 3;
  const unsigned short* aP = A + (size_t)(mtile + srow) * 1024 + scol;
  const unsigned short* bP0 = WgT + (size_t)(nb * 64 + srow) * 1024 + scol;
  const unsigned short* bP1 = WgT + (size_t)(1024 + nb * 64 + srow) * 1024 + scol;
  const int lo = srow * 32 + scol;

  gload_lds16(aP, &sA[0][lo]);
  gload_lds16(aP + 64 * 1024, &sA[0][lo + 64 * 32]);
  gload_lds16(bP0, &sB[0][lo]);
  gload_lds16(bP1, &sB[0][lo + 64 * 32]);
  __syncthreads();

  f32x4 acc[2][8] = {};
  for (int kt = 0; kt < 32; ++kt) {
    const int cur = kt & 1;
    if (kt + 1 < 32) {
      const int ko = (kt + 1) * 32;
      gload_lds16(aP + ko, &sA[1 - cur][lo]);
      gload_lds16(aP + 64 * 1024 + ko, &sA[1 - cur][lo + 64 * 32]);
      gload_lds16(bP0 + ko, &sB[1 - cur][lo]);
      gload_lds16(bP1 + ko, &sB[1 - cur][lo + 64 * 32]);
    }
    bf16x8 af[2], bfr[8];
#pragma unroll
    for (int i = 0; i < 2; ++i)
      af[i] = *(const bf16x8*)&sA[cur][(w * 32 + i * 16 + c) * 32 + g * 8];
#pragma unroll
    for (int j = 0; j < 8; ++j)
      bfr[j] = *(const bf16x8*)&sB[cur][(j * 16 + c) * 32 + g * 8];
#pragma unroll
    for (int i = 0; i < 2; ++i)
#pragma unroll
      for (int j = 0; j < 8; ++j)
        acc[i][j] = __builtin_amdgcn_mfma_f32_16x16x32_bf16(af[i], bfr[j], acc[i][j], 0, 0, 0);
    __syncthreads();
  }

#pragma unroll
  for (int i = 0; i < 2; ++i) {
    int row0 = mtile + w * 32 + i * 16 + (g << 2);
#pragma unroll
    for (int jj = 0; jj < 4; ++jj) {
      int col = nb * 64 + jj * 16 + c;
      float ba = bg[col];
      float bbv = bg[1024 + col];
#pragma unroll
      for (int ri = 0; ri < 4; ++ri) {
        float av = acc[i][jj][ri] + ba;
        float bv = acc[i][jj + 4][ri] + bbv;
        out[(size_t)(row0 + ri) * 1024 + col] = av / (1.f + exp2f(-LOG2E * bv));
      }
    }
  }
}

// ---------------- launch ----------------

extern "C" void kernel_launch(void* const* d_in, const int* in_sizes, int n_in,
                              void* d_out, int out_size, void* d_ws, size_t ws_size,
                              hipStream_t stream) {
  const float* x_q   = (const float*)d_in[0];
  const float* x_kv  = (const float*)d_in[1];
  const float* Wq    = (const float*)d_in[2];
  const float* Wm    = (const float*)d_in[3];
  const float* Wg    = (const float*)d_in[4];
  const float* bg    = (const float*)d_in[5];
  const float* amp   = (const float*)d_in[6];
  const float* off   = (const float*)d_in[7];
  const float* sharp = (const float*)d_in[8];
  float* out = (float*)d_out;

  char* ws = (char*)d_ws;
  size_t o = 0;
  auto alloc = [&](size_t bytes) {
    char* p = ws + o;
    o += (bytes + 255) & ~(size_t)255;
    return p;
  };
  unsigned short* bXq   = (unsigned short*)alloc(4096ull * 1024 * 2);
  unsigned short* bXkv  = (unsigned short*)alloc(4096ull * 1024 * 2);
  unsigned short* bWqT  = (unsigned short*)alloc(1024ull * 1024 * 2);
  unsigned short* bWmT  = (unsigned short*)alloc(2048ull * 1024 * 2);
  unsigned short* bWgT  = (unsigned short*)alloc(2048ull * 1024 * 2);
  float*          biasT = (float*)alloc(16ull * 2047 * 4);
  unsigned short* qbuf  = (unsigned short*)alloc(4096ull * 1024 * 2);
  unsigned short* kbuf  = (unsigned short*)alloc(4096ull * 1024 * 2);
  unsigned short* vtbuf = (unsigned short*)alloc(4096ull * 1024 * 2);
  unsigned short* attnb = (unsigned short*)alloc(4096ull * 1024 * 2);
  if (ws_size < o) return;

  preproc<<<14352, 256, 0, stream>>>(x_q, x_kv, Wq, Wm, Wg, amp, off, sharp,
                                     (ushort4*)bXq, (ushort4*)bXkv,
                                     bWqT, bWmT, bWgT, biasT);
  qkv_gemm<<<dim3(32, 24), 256, 0, stream>>>(bXq, bXkv, bWqT, bWmT, qbuf, kbuf, vtbuf);
  attn_kernel<<<dim3(64, 8), 512, 0, stream>>>(qbuf, kbuf, vtbuf, biasT, attnb);
  out_gemm<<<dim3(32, 16), 256, 0, stream>>>(attnb, bWgT, bg, out);
}

// Round 9
// 208.568 us; speedup vs baseline: 1.1127x; 1.0380x over previous
//
#include <hip/hip_runtime.h>
#include <cstdint>
#include <cstddef>

typedef __attribute__((ext_vector_type(8))) short bf16x8;
typedef __attribute__((ext_vector_type(4))) float f32x4;

#define LOG2E 1.44269504f

__device__ __forceinline__ unsigned short f2bf(float x) {
  unsigned int u = __float_as_uint(x);
  u += 0x7FFFu + ((u >> 16) & 1u);   // RNE
  return (unsigned short)(u >> 16);
}
__device__ __forceinline__ unsigned short f2bf_trunc(float x) {
  return (unsigned short)(__float_as_uint(x) >> 16);
}

__device__ __forceinline__ void gload_lds16(const void* g, void* l) {
  __builtin_amdgcn_global_load_lds(
      (const __attribute__((address_space(1))) unsigned int*)g,
      (__attribute__((address_space(3))) unsigned int*)l, 16, 0, 0);
}

// ---------------- preprocessing: one merged dispatch ----------------

__global__ void preproc(const float* __restrict__ x_q, const float* __restrict__ x_kv,
                        const float* __restrict__ Wq, const float* __restrict__ Wm,
                        const float* __restrict__ Wg,
                        const float* __restrict__ amp, const float* __restrict__ off,
                        const float* __restrict__ sharp,
                        ushort4* __restrict__ bXq, ushort4* __restrict__ bXkv,
                        unsigned short* __restrict__ dWq, unsigned short* __restrict__ dWm,
                        unsigned short* __restrict__ dWg, float* __restrict__ tab) {
  __shared__ float tile[32][33];
  const int blk = blockIdx.x;
  if (blk < 8192) {
    int i = blk * 256 + threadIdx.x;
    float4 v;
    ushort4* d;
    if (i < (1 << 20)) { v = ((const float4*)x_q)[i]; d = bXq + i; }
    else { int j = i - (1 << 20); v = ((const float4*)x_kv)[j]; d = bXkv + j; }
    ushort4 o;
    o.x = f2bf(v.x); o.y = f2bf(v.y); o.z = f2bf(v.z); o.w = f2bf(v.w);
    *d = o;
  } else if (blk < 14336) {
    int idx = blk - 8192;
    int z = idx >> 11, rem = idx & 2047;
    int bx = rem & 63, by = rem >> 6;
    const float* src = z == 0 ? Wq : (z == 1 ? Wm : Wg);
    unsigned short* dst = z == 0 ? dWq : (z == 1 ? dWm : dWg);
    int N = z == 0 ? 1024 : 2048;
    int nb = bx * 32, kb = by * 32;
    if (nb >= N) return;
    int tx = threadIdx.x & 31, ty = threadIdx.x >> 5;
#pragma unroll
    for (int r = ty; r < 32; r += 8)
      tile[r][tx] = src[(size_t)(kb + r) * N + nb + tx];
    __syncthreads();
#pragma unroll
    for (int r = ty; r < 32; r += 8)
      dst[(size_t)(nb + r) * 1024 + kb + tx] = f2bf(tile[tx][r]);
  } else {
    int h = blk - 14336;
    for (int idx = threadIdx.x; idx < 2047; idx += 256) {
      float d = (float)(idx - 1023);
      float acc = 0.f;
#pragma unroll
      for (int k = 0; k < 21; ++k) {
        float dd = d - off[h * 21 + k];
        acc += amp[h * 21 + k] * __expf(-fabsf(sharp[h * 21 + k]) * dd * dd);
      }
      tab[h * 2047 + idx] = acc * LOG2E;
    }
  }
}

// ---------------- fused QKV GEMM (R8: XCD A-locality grid) ----------------
// grid (32, 24): x = M-tile -> XCD = mtile%8 (A L2-resident per XCD).

__global__ __launch_bounds__(256)
void qkv_gemm(const unsigned short* __restrict__ Xq,
              const unsigned short* __restrict__ Xkv,
              const unsigned short* __restrict__ WqT,
              const unsigned short* __restrict__ WmT,
              unsigned short* __restrict__ qbuf,
              unsigned short* __restrict__ kbuf,
              unsigned short* __restrict__ vtbuf) {
  __shared__ unsigned short sA[2][128 * 32];
  __shared__ unsigned short sB[2][128 * 32];
  const int bx = blockIdx.y;
  const bool isQ = bx < 8;
  const int ntile = (isQ ? bx : bx - 8) << 7;
  const unsigned short* A = isQ ? Xq : Xkv;
  const unsigned short* B = (isQ ? WqT : WmT) + (size_t)ntile * 1024;
  const int t = threadIdx.x, lane = t & 63, w = t >> 6;
  const int wm = (w >> 1) << 6, wn = (w & 1) << 6;
  const int mtile = blockIdx.x << 7;
  const int c = lane & 15, g = lane >> 4;
  const int srow = t >> 2, scol = (t & 3) << 3;
  const unsigned short* aP = A + (size_t)(mtile + srow) * 1024 + scol;
  const unsigned short* bP = B + (size_t)srow * 1024 + scol;
  const int lo = srow * 32 + scol;

  gload_lds16(aP, &sA[0][lo]);
  gload_lds16(aP + 64 * 1024, &sA[0][lo + 64 * 32]);
  gload_lds16(bP, &sB[0][lo]);
  gload_lds16(bP + 64 * 1024, &sB[0][lo + 64 * 32]);
  __syncthreads();

  f32x4 acc[4][4] = {};
  for (int kt = 0; kt < 32; ++kt) {
    const int cur = kt & 1;
    if (kt + 1 < 32) {
      const int ko = (kt + 1) * 32;
      gload_lds16(aP + ko, &sA[1 - cur][lo]);
      gload_lds16(aP + 64 * 1024 + ko, &sA[1 - cur][lo + 64 * 32]);
      gload_lds16(bP + ko, &sB[1 - cur][lo]);
      gload_lds16(bP + 64 * 1024 + ko, &sB[1 - cur][lo + 64 * 32]);
    }
    bf16x8 af[4], bfr[4];
#pragma unroll
    for (int i = 0; i < 4; ++i) {
      af[i]  = *(const bf16x8*)&sA[cur][(wm + i * 16 + c) * 32 + g * 8];
      bfr[i] = *(const bf16x8*)&sB[cur][(wn + i * 16 + c) * 32 + g * 8];
    }
#pragma unroll
    for (int i = 0; i < 4; ++i)
#pragma unroll
      for (int j = 0; j < 4; ++j)
        acc[i][j] = __builtin_amdgcn_mfma_f32_16x16x32_bf16(af[i], bfr[j], acc[i][j], 0, 0, 0);
    __syncthreads();
  }

  const int row0 = mtile + wm + (g << 2);
  const int col0 = ntile + wn + c;
  if (isQ) {
#pragma unroll
    for (int i = 0; i < 4; ++i)
#pragma unroll
      for (int j = 0; j < 4; ++j) {
        int r = row0 + i * 16, cl = col0 + j * 16;
#pragma unroll
        for (int ri = 0; ri < 4; ++ri)
          qbuf[(size_t)(r + ri) * 1024 + cl] = f2bf(acc[i][j][ri] * (0.125f * LOG2E));
      }
  } else {
#pragma unroll
    for (int i = 0; i < 4; ++i)
#pragma unroll
      for (int j = 0; j < 4; ++j) {
        int r = row0 + i * 16, cl = col0 + j * 16;
        if (cl < 1024) {
#pragma unroll
          for (int ri = 0; ri < 4; ++ri)
            kbuf[(size_t)(r + ri) * 1024 + cl] = f2bf(acc[i][j][ri]);
        } else {
          int d = cl - 1024;
          int hh = d >> 6, dh = d & 63;
          int bb = r >> 10, ll = r & 1023;
          ushort4 pk;
          pk.x = f2bf(acc[i][j][0]);
          pk.y = f2bf(acc[i][j][1]);
          pk.z = f2bf(acc[i][j][2]);
          pk.w = f2bf(acc[i][j][3]);
          *(ushort4*)&vtbuf[((size_t)((bb * 16 + hh) * 64 + dh) << 10) + ll] = pk;
        }
      }
  }
}

// ---------------- flash attention v7: v6 + bias loads software-pipelined ----------------
// Bias for iter kv+1 is loaded into regs during iter kv; the barrier's vmcnt(0)
// drain guarantees arrival -> zero exposed VMEM latency in the C-init.

__global__ __launch_bounds__(512)
void attn_kernel(const unsigned short* __restrict__ qbuf,
                 const unsigned short* __restrict__ kbuf,
                 const unsigned short* __restrict__ vtbuf,
                 const float* __restrict__ biasTab,
                 unsigned short* __restrict__ attnb) {
  const int h = blockIdx.x & 15, b = blockIdx.x >> 4, qt = blockIdx.y;
  __shared__ unsigned short sK[2][64 * 64];
  __shared__ unsigned short sV[3][64 * 64];
  __shared__ unsigned short sP[2][128 * 64];
  __shared__ float sLsum[2][128];
  const int t = threadIdx.x, lane = t & 63, w = t >> 6;
  const int c = lane & 15, g = lane >> 4;
  const int rg = w >> 1, cg = w & 1;

  const int r = t >> 3, ch = (t & 7) ^ (r & 7);

  const unsigned short* qsrc = qbuf + (size_t)(b * 1024 + qt * 128) * 1024 + h * 64;
  const unsigned short* ksrc = kbuf + (size_t)(b * 1024) * 1024 + h * 64;
  const unsigned short* vsrc = vtbuf + (size_t)((b * 16 + h) * 64) * 1024;

  unsigned short* sQ = &sP[0][0];
  gload_lds16(qsrc + (size_t)r * 1024 + ch * 8, &sQ[t * 8]);
  gload_lds16(qsrc + (size_t)(r + 64) * 1024 + ch * 8, &sQ[4096 + t * 8]);
  gload_lds16(ksrc + (size_t)r * 1024 + ch * 8, &sK[0][t * 8]);
  gload_lds16(vsrc + (size_t)r * 1024 + ch * 8, &sV[0][t * 8]);

  const float* bb = biasTab + h * 2047 + 1023 + cg * 32 + c - qt * 128 - rg * 32 - g * 4;

  // preload bias for kv=0 (overlaps the staging loads above)
  float bc[2][2][4];
#pragma unroll
  for (int rf = 0; rf < 2; ++rf)
#pragma unroll
    for (int nf = 0; nf < 2; ++nf)
#pragma unroll
      for (int ri = 0; ri < 4; ++ri)
        bc[rf][nf][ri] = bb[(nf - rf) * 16 - ri];

  __syncthreads();

  bf16x8 aq[2][2];
#pragma unroll
  for (int rf = 0; rf < 2; ++rf) {
    int row = rg * 32 + rf * 16 + c;
#pragma unroll
    for (int ks = 0; ks < 2; ++ks)
      aq[rf][ks] = *(const bf16x8*)&sQ[row * 64 + (((ks * 4 + g) ^ (row & 7)) * 8)];
  }
  __syncthreads();

  f32x4 o[2][2] = {};
  float lsum[2][4] = {};

  int vcur = 0, vnx = 1;
  for (int kv = 0; kv < 16; ++kv) {
    const int cur = kv & 1;

    // C-init from pre-loaded bias regs
    f32x4 s[2][2];
#pragma unroll
    for (int rf = 0; rf < 2; ++rf)
#pragma unroll
      for (int nf = 0; nf < 2; ++nf)
#pragma unroll
        for (int ri = 0; ri < 4; ++ri)
          s[rf][nf][ri] = bc[rf][nf][ri];

    if (kv + 1 < 16) {
      gload_lds16(ksrc + (size_t)((kv + 1) * 64 + r) * 1024 + ch * 8, &sK[1 - cur][t * 8]);
      gload_lds16(vsrc + (size_t)r * 1024 + (kv + 1) * 64 + ch * 8, &sV[vnx][t * 8]);
      // bias prefetch for next iter (lands by the barrier's vmcnt drain)
      const float* bk = bb + (kv + 1) * 64;
#pragma unroll
      for (int rf = 0; rf < 2; ++rf)
#pragma unroll
        for (int nf = 0; nf < 2; ++nf)
#pragma unroll
          for (int ri = 0; ri < 4; ++ri)
            bc[rf][nf][ri] = bk[(nf - rf) * 16 - ri];
    }

#pragma unroll
    for (int nf = 0; nf < 2; ++nf) {
      int krow = cg * 32 + nf * 16 + c;
      bf16x8 k0 = *(const bf16x8*)&sK[cur][krow * 64 + (((g) ^ (krow & 7)) * 8)];
      bf16x8 k1 = *(const bf16x8*)&sK[cur][krow * 64 + (((4 + g) ^ (krow & 7)) * 8)];
#pragma unroll
      for (int rf = 0; rf < 2; ++rf) {
        s[rf][nf] = __builtin_amdgcn_mfma_f32_16x16x32_bf16(aq[rf][0], k0, s[rf][nf], 0, 0, 0);
        s[rf][nf] = __builtin_amdgcn_mfma_f32_16x16x32_bf16(aq[rf][1], k1, s[rf][nf], 0, 0, 0);
      }
    }

#pragma unroll
    for (int rf = 0; rf < 2; ++rf)
#pragma unroll
      for (int nf = 0; nf < 2; ++nf)
#pragma unroll
        for (int ri = 0; ri < 4; ++ri) {
          float e = exp2f(s[rf][nf][ri]);
          lsum[rf][ri] += e;
          int prow = rg * 32 + rf * 16 + g * 4 + ri;
          int chunk = cg * 4 + nf * 2 + (c >> 3);
          sP[cur][prow * 64 + ((chunk ^ (prow & 7)) * 8) + (c & 7)] = f2bf_trunc(e);
        }
    __syncthreads();

    bf16x8 ap[2][2];
#pragma unroll
    for (int rf = 0; rf < 2; ++rf) {
      int row = rg * 32 + rf * 16 + c;
#pragma unroll
      for (int ks = 0; ks < 2; ++ks)
        ap[rf][ks] = *(const bf16x8*)&sP[cur][row * 64 + (((ks * 4 + g) ^ (row & 7)) * 8)];
    }
#pragma unroll
    for (int df = 0; df < 2; ++df) {
      int vrow = cg * 32 + df * 16 + c;
      bf16x8 v0 = *(const bf16x8*)&sV[vcur][vrow * 64 + (((g) ^ (vrow & 7)) * 8)];
      bf16x8 v1 = *(const bf16x8*)&sV[vcur][vrow * 64 + (((4 + g) ^ (vrow & 7)) * 8)];
#pragma unroll
      for (int rf = 0; rf < 2; ++rf) {
        o[rf][df] = __builtin_amdgcn_mfma_f32_16x16x32_bf16(ap[rf][0], v0, o[rf][df], 0, 0, 0);
        o[rf][df] = __builtin_amdgcn_mfma_f32_16x16x32_bf16(ap[rf][1], v1, o[rf][df], 0, 0, 0);
      }
    }
    vcur = vnx;
    vnx = (vnx == 2) ? 0 : vnx + 1;
  }

#pragma unroll
  for (int off = 1; off < 16; off <<= 1)
#pragma unroll
    for (int rf = 0; rf < 2; ++rf)
#pragma unroll
      for (int ri = 0; ri < 4; ++ri)
        lsum[rf][ri] += __shfl_xor(lsum[rf][ri], off, 64);
  if (c == 0) {
#pragma unroll
    for (int rf = 0; rf < 2; ++rf)
#pragma unroll
      for (int ri = 0; ri < 4; ++ri)
        sLsum[cg][rg * 32 + rf * 16 + g * 4 + ri] = lsum[rf][ri];
  }
  __syncthreads();

  unsigned short* obase = attnb +
      (size_t)(b * 1024 + qt * 128 + rg * 32 + g * 4) * 1024 + h * 64 + cg * 32 + c;
#pragma unroll
  for (int rf = 0; rf < 2; ++rf)
#pragma unroll
    for (int ri = 0; ri < 4; ++ri) {
      int row = rg * 32 + rf * 16 + g * 4 + ri;
      float rinv = 1.0f / (sLsum[0][row] + sLsum[1][row]);
#pragma unroll
      for (int df = 0; df < 2; ++df)
        obase[(size_t)(rf * 16 + ri) * 1024 + df * 16] = f2bf(o[rf][df][ri] * rinv);
    }
}

// ---------------- output GEMM (R6's v5 body, XCD A-locality grid) ----------------
// tile 64M x 64 N-pairs, (256,4) -> 4 blocks/CU; grid (64,16): x = M-tile -> XCD = mtile%8.

__global__ __launch_bounds__(256, 4)
void out_gemm(const unsigned short* __restrict__ A,
              const unsigned short* __restrict__ WgT,
              const float* __restrict__ bg,
              float* __restrict__ out) {
  __shared__ unsigned short sA[2][64 * 32];
  __shared__ unsigned short sB[2][128 * 32];
  const int nb = blockIdx.y;
  const int mtile = blockIdx.x << 6;
  const int t = threadIdx.x, lane = t & 63, w = t >> 6;
  const int c = lane & 15, g = lane >> 4;
  const int rm = w >> 1, cn = w & 1;
  const int srow = t >> 2, scol = (t & 3) << 3;
  const unsigned short* aP = A + (size_t)(mtile + srow) * 1024 + scol;
  const unsigned short* bP0 = WgT + (size_t)(nb * 64 + srow) * 1024 + scol;
  const unsigned short* bP1 = WgT + (size_t)(1024 + nb * 64 + srow) * 1024 + scol;
  const int lo = srow * 32 + scol;

  gload_lds16(aP, &sA[0][lo]);
  gload_lds16(bP0, &sB[0][lo]);
  gload_lds16(bP1, &sB[0][lo + 64 * 32]);
  __syncthreads();

  f32x4 acc[2][4] = {};
  for (int kt = 0; kt < 32; ++kt) {
    const int cur = kt & 1;
    if (kt + 1 < 32) {
      const int ko = (kt + 1) * 32;
      gload_lds16(aP + ko, &sA[1 - cur][lo]);
      gload_lds16(bP0 + ko, &sB[1 - cur][lo]);
      gload_lds16(bP1 + ko, &sB[1 - cur][lo + 64 * 32]);
    }
    bf16x8 af[2], bfr[4];
#pragma unroll
    for (int i = 0; i < 2; ++i)
      af[i] = *(const bf16x8*)&sA[cur][(rm * 32 + i * 16 + c) * 32 + g * 8];
#pragma unroll
    for (int jj = 0; jj < 2; ++jj) {
      bfr[jj]     = *(const bf16x8*)&sB[cur][(cn * 32 + jj * 16 + c) * 32 + g * 8];
      bfr[jj + 2] = *(const bf16x8*)&sB[cur][(64 + cn * 32 + jj * 16 + c) * 32 + g * 8];
    }
#pragma unroll
    for (int i = 0; i < 2; ++i)
#pragma unroll
      for (int j = 0; j < 4; ++j)
        acc[i][j] = __builtin_amdgcn_mfma_f32_16x16x32_bf16(af[i], bfr[j], acc[i][j], 0, 0, 0);
    __syncthreads();
  }

#pragma unroll
  for (int i = 0; i < 2; ++i) {
    int row0 = mtile + rm * 32 + i * 16 + (g << 2);
#pragma unroll
    for (int jj = 0; jj < 2; ++jj) {
      int col = nb * 64 + cn * 32 + jj * 16 + c;
      float ba = bg[col];
      float bbv = bg[1024 + col];
#pragma unroll
      for (int ri = 0; ri < 4; ++ri) {
        float av = acc[i][jj][ri] + ba;
        float bv = acc[i][jj + 2][ri] + bbv;
        out[(size_t)(row0 + ri) * 1024 + col] = av / (1.f + exp2f(-LOG2E * bv));
      }
    }
  }
}

// ---------------- launch ----------------

extern "C" void kernel_launch(void* const* d_in, const int* in_sizes, int n_in,
                              void* d_out, int out_size, void* d_ws, size_t ws_size,
                              hipStream_t stream) {
  const float* x_q   = (const float*)d_in[0];
  const float* x_kv  = (const float*)d_in[1];
  const float* Wq    = (const float*)d_in[2];
  const float* Wm    = (const float*)d_in[3];
  const float* Wg    = (const float*)d_in[4];
  const float* bg    = (const float*)d_in[5];
  const float* amp   = (const float*)d_in[6];
  const float* off   = (const float*)d_in[7];
  const float* sharp = (const float*)d_in[8];
  float* out = (float*)d_out;

  char* ws = (char*)d_ws;
  size_t o = 0;
  auto alloc = [&](size_t bytes) {
    char* p = ws + o;
    o += (bytes + 255) & ~(size_t)255;
    return p;
  };
  unsigned short* bXq   = (unsigned short*)alloc(4096ull * 1024 * 2);
  unsigned short* bXkv  = (unsigned short*)alloc(4096ull * 1024 * 2);
  unsigned short* bWqT  = (unsigned short*)alloc(1024ull * 1024 * 2);
  unsigned short* bWmT  = (unsigned short*)alloc(2048ull * 1024 * 2);
  unsigned short* bWgT  = (unsigned short*)alloc(2048ull * 1024 * 2);
  float*          biasT = (float*)alloc(16ull * 2047 * 4);
  unsigned short* qbuf  = (unsigned short*)alloc(4096ull * 1024 * 2);
  unsigned short* kbuf  = (unsigned short*)alloc(4096ull * 1024 * 2);
  unsigned short* vtbuf = (unsigned short*)alloc(4096ull * 1024 * 2);
  unsigned short* attnb = (unsigned short*)alloc(4096ull * 1024 * 2);
  if (ws_size < o) return;

  preproc<<<14352, 256, 0, stream>>>(x_q, x_kv, Wq, Wm, Wg, amp, off, sharp,
                                     (ushort4*)bXq, (ushort4*)bXkv,
                                     bWqT, bWmT, bWgT, biasT);
  qkv_gemm<<<dim3(32, 24), 256, 0, stream>>>(bXq, bXkv, bWqT, bWmT, qbuf, kbuf, vtbuf);
  attn_kernel<<<dim3(64, 8), 512, 0, stream>>>(qbuf, kbuf, vtbuf, biasT, attnb);
  out_gemm<<<dim3(64, 16), 256, 0, stream>>>(attnb, bWgT, bg, out);
}